// Round 10
// baseline (940.677 us; speedup 1.0000x reference)
//
#include <hip/hip_runtime.h>
#include <math.h>

#define Bn   32
#define Sn   256
#define En   512
#define Hn   512
#define Wn   512
#define ENCn 1024
#define G4   2048
#define KTOT 1536

// ---------------- workspace layout (float offsets) ----------------
#define OFF_BSUM  0L             // [32][256][512]        4194304
#define OFF_PWX   4194304L       // [8224][2048]         16842752  (pe @ Wx)
#define OFF_PE    21037056L      // [32][257][512]        4210688  (u3 overlays after swx)
#define OFF_U3    21037056L      // [32][256][512]        4194304  (written after swx reads pe)
#define OFF_WHB   25247744L      // [8][512][256]         1048576
#define OFF_W4B   26296320L      // [8cb][128kq][64][4]    262144
#define OFF_GPH   26558464L      // [2][32][2048]          131072
#define OFF_SPART 26689536L      // [2][32][8][256]        131072
#define OFF_STATE 26820608L      // 8192 ints
// total ~26828800 floats ~= 107.3 MB
// state ints: gflag[b][16] @ 16*b (init 1), sflag[b][16] @ 512+16*b (init 0)

typedef unsigned long long u64t;

__device__ __forceinline__ float aload(const float* p) {
    return __hip_atomic_load(p, __ATOMIC_RELAXED, __HIP_MEMORY_SCOPE_AGENT);
}
__device__ __forceinline__ void astore(float* p, float v) {
    __hip_atomic_store(p, v, __ATOMIC_RELAXED, __HIP_MEMORY_SCOPE_AGENT);
}
__device__ __forceinline__ int aiload(const int* p) {
    return __hip_atomic_load(p, __ATOMIC_RELAXED, __HIP_MEMORY_SCOPE_AGENT);
}
__device__ __forceinline__ void aistore(int* p, int v) {
    __hip_atomic_store(p, v, __ATOMIC_RELAXED, __HIP_MEMORY_SCOPE_AGENT);
}
__device__ __forceinline__ u64t aload64(const u64t* p) {
    return __hip_atomic_load(p, __ATOMIC_RELAXED, __HIP_MEMORY_SCOPE_AGENT);
}
__device__ __forceinline__ void astore64(u64t* p, u64t v) {
    __hip_atomic_store(p, v, __ATOMIC_RELAXED, __HIP_MEMORY_SCOPE_AGENT);
}
__device__ __forceinline__ u64t pack2(float a, float b) {
    return (u64t)__float_as_uint(a) | ((u64t)__float_as_uint(b) << 32);
}
__device__ __forceinline__ float lo32(u64t v) { return __uint_as_float((unsigned)(v & 0xffffffffu)); }
__device__ __forceinline__ float hi32(u64t v) { return __uint_as_float((unsigned)(v >> 32)); }

// ---------------- init: zero gph, set flags ----------------
__global__ void init_kernel(float* __restrict__ gph, int* __restrict__ state)
{
    int i = blockIdx.x * blockDim.x + threadIdx.x;
    if (i < 131072) gph[i] = 0.0f;
    if (i < 8192) state[i] = (i < 512) ? 1 : 0;   // gflag=1 (gph(1)=h0@Wh=0 pre-zeroed), sflag=0
}

// ---------------- weight repack: WhB [8][512][256], W4B [8][128][64][4] ----------------
__global__ void wtrans_kernel(const float* __restrict__ Wh, const float* __restrict__ W4,
                              float* __restrict__ WhB, float* __restrict__ W4B)
{
    int idx = blockIdx.x * 256 + threadIdx.x;
    if (idx < 1048576) {
        const int c = idx & 255, k = (idx >> 8) & 511, cb = idx >> 17;
        WhB[idx] = Wh[(long)k * G4 + cb * 256 + c];
    }
    if (idx < 262144) {
        const int cc = idx & 3, l = (idx >> 2) & 63, kq = (idx >> 8) & 127, cb = idx >> 15;
        const int k = 4 * kq + cc, j = cb * 64 + l;
        W4B[idx] = W4[(long)k * Wn + j];
    }
}

// ---------------- pe: parallel prefix sums of inp over s ----------------
__global__ void pe1_kernel(const int* __restrict__ wid, const float* __restrict__ emb,
                           float* __restrict__ pb)
{
    const int b = blockIdx.x, blk = blockIdx.y;
    __shared__ int wids[16];
    if (threadIdx.x < 16) wids[threadIdx.x] = wid[b * Sn + blk * 16 + threadIdx.x];
    __syncthreads();
    float a0 = 0.f, a1 = 0.f;
    for (int s = 0; s < 16; ++s) {
        const float* r = emb + (long)wids[s] * En;
        a0 += r[threadIdx.x]; a1 += r[threadIdx.x + 256];
    }
    pb[((long)b * 16 + blk) * En + threadIdx.x] = a0;
    pb[((long)b * 16 + blk) * En + threadIdx.x + 256] = a1;
}

__global__ void pe2_kernel(const int* __restrict__ wid, const float* __restrict__ emb,
                           const float* __restrict__ pb, float* __restrict__ pe)
{
    const int b = blockIdx.x, blk = blockIdx.y;
    __shared__ int wids[16];
    if (threadIdx.x < 16) wids[threadIdx.x] = wid[b * Sn + blk * 16 + threadIdx.x];
    __syncthreads();
    float a0 = 0.f, a1 = 0.f;
    for (int j = 0; j < blk; ++j) {
        a0 += pb[((long)b * 16 + j) * En + threadIdx.x];
        a1 += pb[((long)b * 16 + j) * En + threadIdx.x + 256];
    }
    float* base = pe + (long)b * 257 * En;
    if (blk == 0) { base[threadIdx.x] = 0.f; base[threadIdx.x + 256] = 0.f; }
    for (int s = 0; s < 16; ++s) {
        const float* r = emb + (long)wids[s] * En;
        a0 += r[threadIdx.x]; a1 += r[threadIdx.x + 256];
        float* o = base + (long)(blk * 16 + s + 1) * En;
        o[threadIdx.x] = a0; o[threadIdx.x + 256] = a1;
    }
}

// ---------------- bsum = enc@W1 + emb[wid]@W2 ----------------
__global__ __launch_bounds__(256) void bsum_gemm(
    const float* __restrict__ enc, const int* __restrict__ wid,
    const float* __restrict__ emb, const float* __restrict__ W1,
    const float* __restrict__ W2, float* __restrict__ bsum)
{
    __shared__ float As[16][68];
    __shared__ float Bs[16][68];
    const int tid  = threadIdx.x;
    const int row0 = blockIdx.y * 64;
    const int col0 = blockIdx.x * 64;
    const int tm0  = (tid & 15) * 4;
    const int tn0  = (tid >> 4) * 4;
    const int la_r = tid >> 2;
    const int la_k = (tid & 3) * 4;
    const int lb_k = tid >> 4;
    const int lb_n = (tid & 15) * 4;

    float acc[4][4];
#pragma unroll
    for (int i = 0; i < 4; i++)
#pragma unroll
        for (int j = 0; j < 4; j++) acc[i][j] = 0.0f;

    for (int k0 = 0; k0 < KTOT; k0 += 16) {
        const int gr = row0 + la_r;
        float4 av;
        if (k0 < ENCn) {
            av = *(const float4*)&enc[(long)gr * ENCn + k0 + la_k];
        } else {
            const int wv = wid[gr];
            av = *(const float4*)&emb[(long)wv * En + (k0 - ENCn) + la_k];
        }
        As[la_k + 0][la_r] = av.x;
        As[la_k + 1][la_r] = av.y;
        As[la_k + 2][la_r] = av.z;
        As[la_k + 3][la_r] = av.w;
        float4 bv;
        if (k0 < ENCn) bv = *(const float4*)&W1[(long)(k0 + lb_k) * Wn + col0 + lb_n];
        else           bv = *(const float4*)&W2[(long)(k0 - ENCn + lb_k) * Wn + col0 + lb_n];
        *(float4*)&Bs[lb_k][lb_n] = bv;
        __syncthreads();
#pragma unroll
        for (int kk = 0; kk < 16; kk++) {
            float4 a = *(const float4*)&As[kk][tm0];
            float4 b = *(const float4*)&Bs[kk][tn0];
            acc[0][0] += a.x * b.x; acc[0][1] += a.x * b.y; acc[0][2] += a.x * b.z; acc[0][3] += a.x * b.w;
            acc[1][0] += a.y * b.x; acc[1][1] += a.y * b.y; acc[1][2] += a.y * b.z; acc[1][3] += a.y * b.w;
            acc[2][0] += a.z * b.x; acc[2][1] += a.z * b.y; acc[2][2] += a.z * b.z; acc[2][3] += a.z * b.w;
            acc[3][0] += a.w * b.x; acc[3][1] += a.w * b.y; acc[3][2] += a.w * b.z; acc[3][3] += a.w * b.w;
        }
        __syncthreads();
    }
#pragma unroll
    for (int i = 0; i < 4; i++) {
        float4 o = make_float4(acc[i][0], acc[i][1], acc[i][2], acc[i][3]);
        *(float4*)&bsum[(long)(row0 + tm0 + i) * Wn + col0 + tn0] = o;
    }
}

// ---------------- PWX = pe @ Wx  (M=8224, N=2048, K=512) ----------------
__global__ __launch_bounds__(256) void swx_gemm(
    const float* __restrict__ pe, const float* __restrict__ Wx, float* __restrict__ PWX)
{
    __shared__ float As[16][68];
    __shared__ float Bs[16][68];
    const int tid  = threadIdx.x;
    const int row0 = blockIdx.y * 64;
    const int col0 = blockIdx.x * 64;
    const int tm0  = (tid & 15) * 4;
    const int tn0  = (tid >> 4) * 4;
    const int la_r = tid >> 2;
    const int la_k = (tid & 3) * 4;
    const int lb_k = tid >> 4;
    const int lb_n = (tid & 15) * 4;

    float acc[4][4];
#pragma unroll
    for (int i = 0; i < 4; i++)
#pragma unroll
        for (int j = 0; j < 4; j++) acc[i][j] = 0.0f;

    for (int k0 = 0; k0 < 512; k0 += 16) {
        int gr = row0 + la_r; if (gr > 8223) gr = 8223;
        float4 av = *(const float4*)&pe[(long)gr * En + k0 + la_k];
        As[la_k + 0][la_r] = av.x;
        As[la_k + 1][la_r] = av.y;
        As[la_k + 2][la_r] = av.z;
        As[la_k + 3][la_r] = av.w;
        *(float4*)&Bs[lb_k][lb_n] = *(const float4*)&Wx[(long)(k0 + lb_k) * G4 + col0 + lb_n];
        __syncthreads();
#pragma unroll
        for (int kk = 0; kk < 16; kk++) {
            float4 a = *(const float4*)&As[kk][tm0];
            float4 b = *(const float4*)&Bs[kk][tn0];
            acc[0][0] += a.x * b.x; acc[0][1] += a.x * b.y; acc[0][2] += a.x * b.z; acc[0][3] += a.x * b.w;
            acc[1][0] += a.y * b.x; acc[1][1] += a.y * b.y; acc[1][2] += a.y * b.z; acc[1][3] += a.y * b.w;
            acc[2][0] += a.z * b.x; acc[2][1] += a.z * b.y; acc[2][2] += a.z * b.z; acc[2][3] += a.z * b.w;
            acc[3][0] += a.w * b.x; acc[3][1] += a.w * b.y; acc[3][2] += a.w * b.z; acc[3][3] += a.w * b.w;
        }
        __syncthreads();
    }
#pragma unroll
    for (int i = 0; i < 4; i++) {
        const int r = row0 + tm0 + i;
        if (r < 8224) {
            float4 o = make_float4(acc[i][0], acc[i][1], acc[i][2], acc[i][3]);
            *(float4*)&PWX[(long)r * G4 + col0 + tn0] = o;
        }
    }
}

// ---------------- u3 = emb[wid]@W3 (overlays pe region) ----------------
__global__ __launch_bounds__(256) void u3_gemm(
    const int* __restrict__ wid, const float* __restrict__ emb,
    const float* __restrict__ W3, float* __restrict__ u3)
{
    __shared__ float As[16][68];
    __shared__ float Bs[16][68];
    const int tid  = threadIdx.x;
    const int row0 = blockIdx.y * 64;
    const int col0 = blockIdx.x * 64;
    const int tm0  = (tid & 15) * 4;
    const int tn0  = (tid >> 4) * 4;
    const int la_r = tid >> 2;
    const int la_k = (tid & 3) * 4;
    const int lb_k = tid >> 4;
    const int lb_n = (tid & 15) * 4;

    float acc[4][4];
#pragma unroll
    for (int i = 0; i < 4; i++)
#pragma unroll
        for (int j = 0; j < 4; j++) acc[i][j] = 0.0f;

    for (int k0 = 0; k0 < 512; k0 += 16) {
        const int gr = row0 + la_r;
        const int wv = wid[gr];
        float4 av = *(const float4*)&emb[(long)wv * En + k0 + la_k];
        As[la_k + 0][la_r] = av.x;
        As[la_k + 1][la_r] = av.y;
        As[la_k + 2][la_r] = av.z;
        As[la_k + 3][la_r] = av.w;
        *(float4*)&Bs[lb_k][lb_n] = *(const float4*)&W3[(long)(k0 + lb_k) * Wn + col0 + lb_n];
        __syncthreads();
#pragma unroll
        for (int kk = 0; kk < 16; kk++) {
            float4 a = *(const float4*)&As[kk][tm0];
            float4 b = *(const float4*)&Bs[kk][tn0];
            acc[0][0] += a.x * b.x; acc[0][1] += a.x * b.y; acc[0][2] += a.x * b.z; acc[0][3] += a.x * b.w;
            acc[1][0] += a.y * b.x; acc[1][1] += a.y * b.y; acc[1][2] += a.y * b.z; acc[1][3] += a.y * b.w;
            acc[2][0] += a.z * b.x; acc[2][1] += a.z * b.y; acc[2][2] += a.z * b.z; acc[2][3] += a.z * b.w;
            acc[3][0] += a.w * b.x; acc[3][1] += a.w * b.y; acc[3][2] += a.w * b.z; acc[3][3] += a.w * b.w;
        }
        __syncthreads();
    }
#pragma unroll
    for (int i = 0; i < 4; i++) {
        float4 o = make_float4(acc[i][0], acc[i][1], acc[i][2], acc[i][3]);
        *(float4*)&u3[(long)(row0 + tm0 + i) * Wn + col0 + tn0] = o;
    }
}

// ---------------- decode: 32 batches x 8 WGs, fully batch-local dataflow ----------------
// WG (b = wg>>3, cb2 = wg&7). Per step t (active):
//   A: poll 8 gflag>=t; load PWX[b][bd] row -> LDS, u3 slice, gph (4 u64/thread)
//   B: LSTM (redundant-full; h,c in LDS); no publish
//   C: u4 (64-col slice, W4 in LDS) -> q
//   D: scores rows>=bd (64-col slice) -> spart[t&1]
//   E: gph(t+1) = h @ Wh-slice (256 cols, L2-resident WhB)
//   F: drain; set sflag=t, gflag=t+1; poll 8 sflag>=t; read spart; redundant argmax
//   G: decision locally; owner writes out; exit when bond>=Sn.
__global__ __launch_bounds__(256) void decode_kernel(
    const float* __restrict__ bias, const float* __restrict__ vt1,
    const float* __restrict__ bsum, const float* __restrict__ u3,
    const float* __restrict__ PWX,  const float* __restrict__ WhB,
    const float* __restrict__ W4B,  float* __restrict__ gphbuf,
    float* __restrict__ spart, int* __restrict__ state,
    const float* __restrict__ hn0, float* __restrict__ out)
{
    __shared__ __align__(16) float wlds[32768];    // W4 slice 128 KB
    __shared__ __align__(16) float pwx[2][2048];   // bond/last PWX rows
    __shared__ __align__(16) float hld[512];
    __shared__ __align__(16) float cld[512];
    __shared__ __align__(16) float sgph[4][256];
    __shared__ __align__(16) float sred4[4][64];
    __shared__ float qv[64];
    __shared__ float s_svt[64];
    __shared__ float s_wv[4];
    __shared__ int   s_wi[4];

    const int wg   = blockIdx.x;
    const int tid  = threadIdx.x;
    const int lane = tid & 63;
    const int wv   = tid >> 6;
    const int b    = wg >> 3;
    const int cb2  = wg & 7;

    int* gflag = state;            // [b][16]
    int* sflag = state + 512;      // [b][16]
    u64t* gph64 = (u64t*)gphbuf;
    const float4* W4B4 = (const float4*)W4B;
    float4* wlds4 = (float4*)wlds;
    const float4* h4 = (const float4*)hld;

    // preload W4 slice, vt slice, h/c init, pwx_ls = PWX[b][0]
    {
        const float4* src = W4B4 + (long)cb2 * 8192;
        for (int i = tid; i < 8192; i += 256) wlds4[i] = src[i];
    }
    if (tid < 64) s_svt[tid] = vt1[cb2 * 64 + tid];
    cld[tid]       = hn0[b * Hn + tid];
    cld[256 + tid] = hn0[b * Hn + 256 + tid];
    hld[tid] = 0.f; hld[256 + tid] = 0.f;
    {
        const float4* pr = (const float4*)(PWX + (long)b * 257 * G4);
        float4* d = (float4*)pwx[0];
        for (int i = tid; i < 512; i += 256) d[i] = pr[i];
    }
    const float2* bias2 = (const float2*)bias;
    const float2 bi  = bias2[tid];
    const float2 bf  = bias2[256 + tid];
    const float2 bg_ = bias2[512 + tid];
    const float2 bo  = bias2[768 + tid];
    __syncthreads();

    int bd = 0, ls = 0;

    for (int t = 1; t <= Sn; ++t) {
        const int cur = t & 1, prv = cur ^ 1;

        // ---- A: wait for gph(t), then load inputs ----
        if (tid < 8) {
            const int* g = gflag + 16 * b + tid;
            while (aiload(g) < t) __builtin_amdgcn_s_sleep(1);
        }
        __syncthreads();
        // PWX[b][bd] -> pwx[cur]
        {
            const float4* pr = (const float4*)(PWX + ((long)b * 257 + bd) * G4);
            float4* d = (float4*)pwx[cur];
            for (int i = tid; i < 512; i += 256) d[i] = pr[i];
        }
        float u3v = 0.f;
        if (tid < 64) u3v = aload(&u3[((long)b * Sn + bd) * Wn + cb2 * 64 + tid]);
        const long gb = (long)cur * 32768 + (long)b * 1024;
        const u64t g0 = aload64(&gph64[gb + tid]);
        const u64t g1 = aload64(&gph64[gb + 256 + tid]);
        const u64t g2 = aload64(&gph64[gb + 512 + tid]);
        const u64t g3 = aload64(&gph64[gb + 768 + tid]);
        __syncthreads();   // pwx[cur] complete

        // ---- B: LSTM (redundant full) ----
        {
            const float inv = 1.0f / (float)max(bd - ls, 1);
            const int j0 = 2 * tid, j1 = j0 + 1;
            const float igA = (pwx[cur][j0]        - pwx[prv][j0])        * inv + lo32(g0) + bi.x;
            const float igB = (pwx[cur][j1]        - pwx[prv][j1])        * inv + hi32(g0) + bi.y;
            const float fgA = (pwx[cur][512 + j0]  - pwx[prv][512 + j0])  * inv + lo32(g1) + bf.x;
            const float fgB = (pwx[cur][512 + j1]  - pwx[prv][512 + j1])  * inv + hi32(g1) + bf.y;
            const float ggA = (pwx[cur][1024 + j0] - pwx[prv][1024 + j0]) * inv + lo32(g2) + bg_.x;
            const float ggB = (pwx[cur][1024 + j1] - pwx[prv][1024 + j1]) * inv + hi32(g2) + bg_.y;
            const float ogA = (pwx[cur][1536 + j0] - pwx[prv][1536 + j0]) * inv + lo32(g3) + bo.x;
            const float ogB = (pwx[cur][1536 + j1] - pwx[prv][1536 + j1]) * inv + hi32(g3) + bo.y;
            const float sfA = 1.f / (1.f + expf(-fgA));
            const float siA = 1.f / (1.f + expf(-igA));
            const float soA = 1.f / (1.f + expf(-ogA));
            const float cnA = sfA * cld[j0] + siA * tanhf(ggA);
            const float h2A = soA * tanhf(cnA);
            const float sfB = 1.f / (1.f + expf(-fgB));
            const float siB = 1.f / (1.f + expf(-igB));
            const float soB = 1.f / (1.f + expf(-ogB));
            const float cnB = sfB * cld[j1] + siB * tanhf(ggB);
            const float h2B = soB * tanhf(cnB);
            cld[j0] = cnA; hld[j0] = h2A;
            cld[j1] = cnB; hld[j1] = h2B;
        }
        __syncthreads();   // h ready

        // ---- C: u4 slice (64 cols), wave K-split ----
        {
            float acc = 0.f;
            const float4* wr = wlds4 + (wv * 32) * 64 + lane;
#pragma unroll 8
            for (int kq = 0; kq < 32; ++kq) {
                const float4 w = wr[kq * 64];
                const float4 hv = h4[wv * 32 + kq];
                acc += w.x * hv.x + w.y * hv.y + w.z * hv.z + w.w * hv.w;
            }
            sred4[wv][lane] = acc;
        }
        __syncthreads();
        if (tid < 64) qv[tid] = sred4[0][tid] + sred4[1][tid] + sred4[2][tid] + sred4[3][tid] + u3v;
        __syncthreads();

        // ---- D: partial scores (row = tid, 64-col slice) ----
        if (tid >= bd) {
            const float* row = bsum + ((long)b * Sn + tid) * Wn + cb2 * 64;
            float a = 0.f;
#pragma unroll 8
            for (int i = 0; i < 64; ++i)
                a += tanhf(row[i] + qv[i]) * s_svt[i];
            astore(&spart[(long)cur * 65536 + (long)b * 2048 + cb2 * 256 + tid], a);
        }

        // ---- E: gph(t+1) slice (256 cols) from L2-resident WhB ----
        {
            float4 acc = make_float4(0.f, 0.f, 0.f, 0.f);
            const float* wb = WhB + (long)cb2 * 131072;
            const int k0 = wv * 128;
#pragma unroll 4
            for (int k = k0; k < k0 + 128; ++k) {
                const float hk = hld[k];
                const float4 w = *(const float4*)&wb[(long)k * 256 + lane * 4];
                acc.x += hk * w.x; acc.y += hk * w.y; acc.z += hk * w.z; acc.w += hk * w.w;
            }
            *(float4*)&sgph[wv][lane * 4] = acc;
        }
        __syncthreads();
        if (tid < 128) {
            const int c0 = 2 * tid, c1 = c0 + 1;
            const float lo = sgph[0][c0] + sgph[1][c0] + sgph[2][c0] + sgph[3][c0];
            const float hi = sgph[0][c1] + sgph[1][c1] + sgph[2][c1] + sgph[3][c1];
            astore64(&gph64[(long)prv * 32768 + (long)b * 1024 + cb2 * 128 + tid], pack2(lo, hi));
        }
        __syncthreads();   // drains spart + gph stores (vmcnt 0)

        // ---- F: flags, exchange, redundant argmax ----
        if (tid == 0) {
            aistore(&sflag[16 * b + cb2], t);
            aistore(&gflag[16 * b + cb2], t + 1);
        }
        if (tid < 8) {
            const int* s = sflag + 16 * b + tid;
            while (aiload(s) < t) __builtin_amdgcn_s_sleep(1);
        }
        __syncthreads();
        float v = -3.402823e38f; int vi = Sn;
        if (tid >= bd) {
            const float* sp = spart + (long)cur * 65536 + (long)b * 2048 + tid;
            float s = 0.f;
#pragma unroll
            for (int k = 0; k < 8; ++k) s += aload(&sp[k * 256]);
            v = s; vi = tid;
        }
#pragma unroll
        for (int off = 32; off; off >>= 1) {
            const float v2 = __shfl_xor(v, off, 64);
            const int   i2 = __shfl_xor(vi, off, 64);
            if (v2 > v || (v2 == v && i2 < vi)) { v = v2; vi = i2; }
        }
        if (lane == 0) { s_wv[wv] = v; s_wi[wv] = vi; }
        __syncthreads();
        {
            float bv = s_wv[0]; int bi_ = s_wi[0];
#pragma unroll
            for (int k = 1; k < 4; ++k)
                if (s_wv[k] > bv || (s_wv[k] == bv && s_wi[k] < bi_)) { bv = s_wv[k]; bi_ = s_wi[k]; }
            const int nb = (bi_ > bd) ? bi_ : bd + 1;
            if (cb2 == 0 && tid == 0 && nb < Sn) out[nb * Bn + b] = 1.0f;
            ls = bd; bd = nb;
        }
        __syncthreads();
        if (bd >= Sn) break;
    }
}

extern "C" void kernel_launch(void* const* d_in, const int* in_sizes, int n_in,
                              void* d_out, int out_size, void* d_ws, size_t ws_size,
                              hipStream_t stream)
{
    const int*   wid  = (const int*)d_in[0];
    const float* enc  = (const float*)d_in[1];
    const float* hn0  = (const float*)d_in[2];
    const float* emb  = (const float*)d_in[3];
    // d_in[4] chunk_emb : unused (uniform score shift, argmax-invariant)
    const float* W1   = (const float*)d_in[5];
    const float* W2   = (const float*)d_in[6];
    const float* W3   = (const float*)d_in[7];
    const float* W4   = (const float*)d_in[8];
    const float* vt1  = (const float*)d_in[9];
    // d_in[10] vt2 : unused
    const float* Wx   = (const float*)d_in[11];
    const float* Wh   = (const float*)d_in[12];
    const float* bias = (const float*)d_in[13];

    float* ws    = (float*)d_ws;
    float* bsum  = ws + OFF_BSUM;
    float* PWX   = ws + OFF_PWX;
    float* pe    = ws + OFF_PE;
    float* pb    = ws + OFF_WHB;      // pb overlay: used before wtrans? NO - wtrans runs first. use bsum region? bsum written later.
    float* u3    = ws + OFF_U3;       // overlays pe (written after swx_gemm consumed pe)
    float* WhB   = ws + OFF_WHB;
    float* W4B   = ws + OFF_W4B;
    float* gph   = ws + OFF_GPH;
    float* spart = ws + OFF_SPART;
    int*   state = (int*)(ws + OFF_STATE);
    float* out   = (float*)d_out;

    // pb (pe block partials, 32*16*512 = 262144 floats) overlays bsum region
    // (bsum_gemm runs after pe2 consumed pb).
    pb = ws + OFF_BSUM;

    (void)hipMemsetAsync(d_out, 0, (size_t)Sn * Bn * sizeof(float), stream);
    hipLaunchKernelGGL(init_kernel, dim3(544), dim3(256), 0, stream, gph, state);
    hipLaunchKernelGGL(wtrans_kernel, dim3(4096), dim3(256), 0, stream, Wh, W4, WhB, W4B);
    hipLaunchKernelGGL(pe1_kernel, dim3(32, 16), dim3(256), 0, stream, wid, emb, pb);
    hipLaunchKernelGGL(pe2_kernel, dim3(32, 16), dim3(256), 0, stream, wid, emb, pb, pe);
    hipLaunchKernelGGL(swx_gemm, dim3(32, 129), dim3(256), 0, stream, pe, Wx, PWX);
    hipLaunchKernelGGL(u3_gemm, dim3(8, 128), dim3(256), 0, stream, wid, emb, W3, u3);
    hipLaunchKernelGGL(bsum_gemm, dim3(8, 128), dim3(256), 0, stream, enc, wid, emb, W1, W2, bsum);

    void* args[] = { (void*)&bias, (void*)&vt1, (void*)&bsum, (void*)&u3, (void*)&PWX,
                     (void*)&WhB, (void*)&W4B, (void*)&gph, (void*)&spart,
                     (void*)&state, (void*)&hn0, (void*)&out };
    (void)hipLaunchCooperativeKernel((void*)decode_kernel, dim3(256), dim3(256), args, 0, stream);
}

// Round 11
// 787.362 us; speedup vs baseline: 1.1947x; 1.1947x over previous
//
#include <hip/hip_runtime.h>
#include <math.h>

#define Bn   32
#define Sn   256
#define En   512
#define Hn   512
#define Wn   512
#define ENCn 1024
#define G4   2048
#define KTOT 1536

// ---------------- workspace layout (float offsets) ----------------
#define OFF_BSUM  0L             // [32][256][512]   4194304  (pb overlays before bsum_gemm)
#define OFF_U3    4194304L       // [32][256][512]   4194304
#define OFF_PE    8388608L       // [32][257][512]   4210688  (live during decode!)
#define OFF_WXB   12599296L      // [8cb][512k][256c] 1048576
#define OFF_WHB   13647872L      // [8cb][512k][256c] 1048576
#define OFF_W4B   14696448L      // [8cb][128kq][64][4] 262144
#define OFF_GXW   14958592L      // [2][32][2048]     131072
#define OFF_GPH   15089664L      // [2][32][2048]     131072
#define OFF_SPART 15220736L      // [2][32][8][256] u64 tagged = 262144 floats
#define OFF_STATE 15482880L      // 8192 ints
// total ~15491072 floats ~= 62 MB
// state ints: gflag[b][16] @ 16*b (init 1); rest unused

typedef unsigned long long u64t;

__device__ __forceinline__ float aload(const float* p) {
    return __hip_atomic_load(p, __ATOMIC_RELAXED, __HIP_MEMORY_SCOPE_AGENT);
}
__device__ __forceinline__ void astore(float* p, float v) {
    __hip_atomic_store(p, v, __ATOMIC_RELAXED, __HIP_MEMORY_SCOPE_AGENT);
}
__device__ __forceinline__ int aiload(const int* p) {
    return __hip_atomic_load(p, __ATOMIC_RELAXED, __HIP_MEMORY_SCOPE_AGENT);
}
__device__ __forceinline__ void aistore(int* p, int v) {
    __hip_atomic_store(p, v, __ATOMIC_RELAXED, __HIP_MEMORY_SCOPE_AGENT);
}
__device__ __forceinline__ u64t aload64(const u64t* p) {
    return __hip_atomic_load(p, __ATOMIC_RELAXED, __HIP_MEMORY_SCOPE_AGENT);
}
__device__ __forceinline__ void astore64(u64t* p, u64t v) {
    __hip_atomic_store(p, v, __ATOMIC_RELAXED, __HIP_MEMORY_SCOPE_AGENT);
}
__device__ __forceinline__ u64t pack2(float a, float b) {
    return (u64t)__float_as_uint(a) | ((u64t)__float_as_uint(b) << 32);
}
__device__ __forceinline__ u64t packtag(float a, int t) {
    return (u64t)__float_as_uint(a) | ((u64t)(unsigned)t << 32);
}
__device__ __forceinline__ float lo32(u64t v) { return __uint_as_float((unsigned)(v & 0xffffffffu)); }
__device__ __forceinline__ float hi32(u64t v) { return __uint_as_float((unsigned)(v >> 32)); }

// ---------------- init (runs every launch: graph-replay determinism) ----------------
__global__ void init_kernel(float* __restrict__ gxw, float* __restrict__ gph,
                            float* __restrict__ sp2, int* __restrict__ state)
{
    int i = blockIdx.x * blockDim.x + threadIdx.x;
    if (i < 131072) { gxw[i] = 0.0f; gph[i] = 0.0f; }
    if (i < 262144) sp2[i] = 0.0f;                    // zero tags
    if (i < 8192) state[i] = (i < 512) ? 1 : 0;       // gflag=1 (gates(1)=0 pre-zeroed)
}

// ---------------- weight repack: WxB/WhB [8][512][256], W4B [8][128][64][4] ----------------
__global__ void wtrans_kernel(const float* __restrict__ Wx, const float* __restrict__ Wh,
                              const float* __restrict__ W4, float* __restrict__ WxB,
                              float* __restrict__ WhB, float* __restrict__ W4B)
{
    int idx = blockIdx.x * 256 + threadIdx.x;
    if (idx < 1048576) {
        const int c = idx & 255, k = (idx >> 8) & 511, cb = idx >> 17;
        WxB[idx] = Wx[(long)k * G4 + cb * 256 + c];
        WhB[idx] = Wh[(long)k * G4 + cb * 256 + c];
    }
    if (idx < 262144) {
        const int cc = idx & 3, l = (idx >> 2) & 63, kq = (idx >> 8) & 127, cb = idx >> 15;
        const int k = 4 * kq + cc, j = cb * 64 + l;
        W4B[idx] = W4[(long)k * Wn + j];
    }
}

// ---------------- pe: parallel prefix sums of inp over s ----------------
__global__ void pe1_kernel(const int* __restrict__ wid, const float* __restrict__ emb,
                           float* __restrict__ pb)
{
    const int b = blockIdx.x, blk = blockIdx.y;
    __shared__ int wids[16];
    if (threadIdx.x < 16) wids[threadIdx.x] = wid[b * Sn + blk * 16 + threadIdx.x];
    __syncthreads();
    float a0 = 0.f, a1 = 0.f;
    for (int s = 0; s < 16; ++s) {
        const float* r = emb + (long)wids[s] * En;
        a0 += r[threadIdx.x]; a1 += r[threadIdx.x + 256];
    }
    pb[((long)b * 16 + blk) * En + threadIdx.x] = a0;
    pb[((long)b * 16 + blk) * En + threadIdx.x + 256] = a1;
}

__global__ void pe2_kernel(const int* __restrict__ wid, const float* __restrict__ emb,
                           const float* __restrict__ pb, float* __restrict__ pe)
{
    const int b = blockIdx.x, blk = blockIdx.y;
    __shared__ int wids[16];
    if (threadIdx.x < 16) wids[threadIdx.x] = wid[b * Sn + blk * 16 + threadIdx.x];
    __syncthreads();
    float a0 = 0.f, a1 = 0.f;
    for (int j = 0; j < blk; ++j) {
        a0 += pb[((long)b * 16 + j) * En + threadIdx.x];
        a1 += pb[((long)b * 16 + j) * En + threadIdx.x + 256];
    }
    float* base = pe + (long)b * 257 * En;
    if (blk == 0) { base[threadIdx.x] = 0.f; base[threadIdx.x + 256] = 0.f; }
    for (int s = 0; s < 16; ++s) {
        const float* r = emb + (long)wids[s] * En;
        a0 += r[threadIdx.x]; a1 += r[threadIdx.x + 256];
        float* o = base + (long)(blk * 16 + s + 1) * En;
        o[threadIdx.x] = a0; o[threadIdx.x + 256] = a1;
    }
}

// ---------------- bsum = enc@W1 + emb[wid]@W2 ----------------
__global__ __launch_bounds__(256) void bsum_gemm(
    const float* __restrict__ enc, const int* __restrict__ wid,
    const float* __restrict__ emb, const float* __restrict__ W1,
    const float* __restrict__ W2, float* __restrict__ bsum)
{
    __shared__ float As[16][68];
    __shared__ float Bs[16][68];
    const int tid  = threadIdx.x;
    const int row0 = blockIdx.y * 64;
    const int col0 = blockIdx.x * 64;
    const int tm0  = (tid & 15) * 4;
    const int tn0  = (tid >> 4) * 4;
    const int la_r = tid >> 2;
    const int la_k = (tid & 3) * 4;
    const int lb_k = tid >> 4;
    const int lb_n = (tid & 15) * 4;

    float acc[4][4];
#pragma unroll
    for (int i = 0; i < 4; i++)
#pragma unroll
        for (int j = 0; j < 4; j++) acc[i][j] = 0.0f;

    for (int k0 = 0; k0 < KTOT; k0 += 16) {
        const int gr = row0 + la_r;
        float4 av;
        if (k0 < ENCn) {
            av = *(const float4*)&enc[(long)gr * ENCn + k0 + la_k];
        } else {
            const int wv = wid[gr];
            av = *(const float4*)&emb[(long)wv * En + (k0 - ENCn) + la_k];
        }
        As[la_k + 0][la_r] = av.x;
        As[la_k + 1][la_r] = av.y;
        As[la_k + 2][la_r] = av.z;
        As[la_k + 3][la_r] = av.w;
        float4 bv;
        if (k0 < ENCn) bv = *(const float4*)&W1[(long)(k0 + lb_k) * Wn + col0 + lb_n];
        else           bv = *(const float4*)&W2[(long)(k0 - ENCn + lb_k) * Wn + col0 + lb_n];
        *(float4*)&Bs[lb_k][lb_n] = bv;
        __syncthreads();
#pragma unroll
        for (int kk = 0; kk < 16; kk++) {
            float4 a = *(const float4*)&As[kk][tm0];
            float4 b = *(const float4*)&Bs[kk][tn0];
            acc[0][0] += a.x * b.x; acc[0][1] += a.x * b.y; acc[0][2] += a.x * b.z; acc[0][3] += a.x * b.w;
            acc[1][0] += a.y * b.x; acc[1][1] += a.y * b.y; acc[1][2] += a.y * b.z; acc[1][3] += a.y * b.w;
            acc[2][0] += a.z * b.x; acc[2][1] += a.z * b.y; acc[2][2] += a.z * b.z; acc[2][3] += a.z * b.w;
            acc[3][0] += a.w * b.x; acc[3][1] += a.w * b.y; acc[3][2] += a.w * b.z; acc[3][3] += a.w * b.w;
        }
        __syncthreads();
    }
#pragma unroll
    for (int i = 0; i < 4; i++) {
        float4 o = make_float4(acc[i][0], acc[i][1], acc[i][2], acc[i][3]);
        *(float4*)&bsum[(long)(row0 + tm0 + i) * Wn + col0 + tn0] = o;
    }
}

// ---------------- u3 = emb[wid]@W3 ----------------
__global__ __launch_bounds__(256) void u3_gemm(
    const int* __restrict__ wid, const float* __restrict__ emb,
    const float* __restrict__ W3, float* __restrict__ u3)
{
    __shared__ float As[16][68];
    __shared__ float Bs[16][68];
    const int tid  = threadIdx.x;
    const int row0 = blockIdx.y * 64;
    const int col0 = blockIdx.x * 64;
    const int tm0  = (tid & 15) * 4;
    const int tn0  = (tid >> 4) * 4;
    const int la_r = tid >> 2;
    const int la_k = (tid & 3) * 4;
    const int lb_k = tid >> 4;
    const int lb_n = (tid & 15) * 4;

    float acc[4][4];
#pragma unroll
    for (int i = 0; i < 4; i++)
#pragma unroll
        for (int j = 0; j < 4; j++) acc[i][j] = 0.0f;

    for (int k0 = 0; k0 < 512; k0 += 16) {
        const int gr = row0 + la_r;
        const int wv = wid[gr];
        float4 av = *(const float4*)&emb[(long)wv * En + k0 + la_k];
        As[la_k + 0][la_r] = av.x;
        As[la_k + 1][la_r] = av.y;
        As[la_k + 2][la_r] = av.z;
        As[la_k + 3][la_r] = av.w;
        *(float4*)&Bs[lb_k][lb_n] = *(const float4*)&W3[(long)(k0 + lb_k) * Wn + col0 + lb_n];
        __syncthreads();
#pragma unroll
        for (int kk = 0; kk < 16; kk++) {
            float4 a = *(const float4*)&As[kk][tm0];
            float4 b = *(const float4*)&Bs[kk][tn0];
            acc[0][0] += a.x * b.x; acc[0][1] += a.x * b.y; acc[0][2] += a.x * b.z; acc[0][3] += a.x * b.w;
            acc[1][0] += a.y * b.x; acc[1][1] += a.y * b.y; acc[1][2] += a.y * b.z; acc[1][3] += a.y * b.w;
            acc[2][0] += a.z * b.x; acc[2][1] += a.z * b.y; acc[2][2] += a.z * b.z; acc[2][3] += a.z * b.w;
            acc[3][0] += a.w * b.x; acc[3][1] += a.w * b.y; acc[3][2] += a.w * b.z; acc[3][3] += a.w * b.w;
        }
        __syncthreads();
    }
#pragma unroll
    for (int i = 0; i < 4; i++) {
        float4 o = make_float4(acc[i][0], acc[i][1], acc[i][2], acc[i][3]);
        *(float4*)&u3[(long)(row0 + tm0 + i) * Wn + col0 + tn0] = o;
    }
}

// ---------------- decode: 32 batches x 8 WGs, batch-local; gates GEMVs in step tail ----------------
// WG (b = wg>>3, cb2 = wg&7):
//   A: poll 8 gflag>=t; load u3 slice + gates gx/gph (u64)
//   B: LSTM (redundant full; h,c in LDS)
//   C: u4 (64-col slice, W4 in LDS) -> qv
//   D: scores rows>=bd -> TAGGED u64 spart2 (tag travels with data: no drain, no flag)
//   F: per-thread poll own row's 8 tags==t; redundant argmax -> local decision
//   TAIL: x=(pe[bd]-pe[ls])/len; gph(t+1)=h@WhB-slice; gxw(t+1)=x@WxB-slice; drain; gflag=t+1
__global__ __launch_bounds__(256) void decode_kernel(
    const float* __restrict__ bias, const float* __restrict__ vt1,
    const float* __restrict__ bsum, const float* __restrict__ u3,
    const float* __restrict__ pe,   const float* __restrict__ WxB,
    const float* __restrict__ WhB,  const float* __restrict__ W4B,
    float* __restrict__ gxwbuf, float* __restrict__ gphbuf,
    u64t* __restrict__ spart2, int* __restrict__ state,
    const float* __restrict__ hn0, float* __restrict__ out)
{
    __shared__ __align__(16) float wlds[32768];    // W4 slice 128 KB
    __shared__ __align__(16) float hld[512];
    __shared__ __align__(16) float cld[512];
    __shared__ __align__(16) float xld[512];
    __shared__ __align__(16) float sgp[4][256];
    __shared__ __align__(16) float sred4[4][64];
    __shared__ float qv[64];
    __shared__ float s_svt[64];
    __shared__ float s_wv[4];
    __shared__ int   s_wi[4];

    const int wg   = blockIdx.x;
    const int tid  = threadIdx.x;
    const int lane = tid & 63;
    const int wv   = tid >> 6;
    const int b    = wg >> 3;
    const int cb2  = wg & 7;

    int* gflag = state;            // [b][16]
    u64t* gxw64 = (u64t*)gxwbuf;   // [2][32][1024] u64
    u64t* gph64 = (u64t*)gphbuf;
    const float4* W4B4 = (const float4*)W4B;
    float4* wlds4 = (float4*)wlds;
    const float4* h4 = (const float4*)hld;
    const float2* pef2 = (const float2*)pe;

    // preload W4 slice, vt slice, h/c init
    {
        const float4* src = W4B4 + (long)cb2 * 8192;
        for (int i = tid; i < 8192; i += 256) wlds4[i] = src[i];
    }
    if (tid < 64) s_svt[tid] = vt1[cb2 * 64 + tid];
    cld[tid]       = hn0[b * Hn + tid];
    cld[256 + tid] = hn0[b * Hn + 256 + tid];
    hld[tid] = 0.f; hld[256 + tid] = 0.f;
    const float2* bias2 = (const float2*)bias;
    const float2 bi  = bias2[tid];
    const float2 bf  = bias2[256 + tid];
    const float2 bg_ = bias2[512 + tid];
    const float2 bo  = bias2[768 + tid];
    __syncthreads();

    int bd = 0, ls = 0;

    for (int t = 1; t <= Sn; ++t) {
        const long cur = (long)(t & 1) * 32768;      // u64 parity offset for gxw/gph
        const long scur = (long)(t & 1) * 65536;     // u64 parity offset for spart2

        // ---- A: wait for gates(t) ----
        if (tid < 8) {
            const int* g = gflag + 16 * b + tid;
            while (aiload(g) < t) __builtin_amdgcn_s_sleep(1);
        }
        __syncthreads();
        float u3v = 0.f;
        if (tid < 64) u3v = aload(&u3[((long)b * Sn + bd) * Wn + cb2 * 64 + tid]);
        const long gb = cur + (long)b * 1024;
        const u64t gx0 = aload64(&gxw64[gb + tid]);
        const u64t gx1 = aload64(&gxw64[gb + 256 + tid]);
        const u64t gx2 = aload64(&gxw64[gb + 512 + tid]);
        const u64t gx3 = aload64(&gxw64[gb + 768 + tid]);
        const u64t gh0 = aload64(&gph64[gb + tid]);
        const u64t gh1 = aload64(&gph64[gb + 256 + tid]);
        const u64t gh2 = aload64(&gph64[gb + 512 + tid]);
        const u64t gh3 = aload64(&gph64[gb + 768 + tid]);

        // ---- B: LSTM (redundant full) ----
        {
            const int j0 = 2 * tid, j1 = j0 + 1;
            const float igA = lo32(gx0) + lo32(gh0) + bi.x;
            const float igB = hi32(gx0) + hi32(gh0) + bi.y;
            const float fgA = lo32(gx1) + lo32(gh1) + bf.x;
            const float fgB = hi32(gx1) + hi32(gh1) + bf.y;
            const float ggA = lo32(gx2) + lo32(gh2) + bg_.x;
            const float ggB = hi32(gx2) + hi32(gh2) + bg_.y;
            const float ogA = lo32(gx3) + lo32(gh3) + bo.x;
            const float ogB = hi32(gx3) + hi32(gh3) + bo.y;
            const float sfA = 1.f / (1.f + expf(-fgA));
            const float siA = 1.f / (1.f + expf(-igA));
            const float soA = 1.f / (1.f + expf(-ogA));
            const float cnA = sfA * cld[j0] + siA * tanhf(ggA);
            const float h2A = soA * tanhf(cnA);
            const float sfB = 1.f / (1.f + expf(-fgB));
            const float siB = 1.f / (1.f + expf(-igB));
            const float soB = 1.f / (1.f + expf(-ogB));
            const float cnB = sfB * cld[j1] + siB * tanhf(ggB);
            const float h2B = soB * tanhf(cnB);
            cld[j0] = cnA; hld[j0] = h2A;
            cld[j1] = cnB; hld[j1] = h2B;
        }
        __syncthreads();

        // ---- C: u4 slice (64 cols), wave K-split ----
        {
            float acc = 0.f;
            const float4* wr = wlds4 + (wv * 32) * 64 + lane;
#pragma unroll 8
            for (int kq = 0; kq < 32; ++kq) {
                const float4 w = wr[kq * 64];
                const float4 hv = h4[wv * 32 + kq];
                acc += w.x * hv.x + w.y * hv.y + w.z * hv.z + w.w * hv.w;
            }
            sred4[wv][lane] = acc;
        }
        __syncthreads();
        if (tid < 64) qv[tid] = sred4[0][tid] + sred4[1][tid] + sred4[2][tid] + sred4[3][tid] + u3v;
        __syncthreads();

        // ---- D: partial scores -> tagged u64 (no drain/flag needed) ----
        if (tid >= bd) {
            const float* row = bsum + ((long)b * Sn + tid) * Wn + cb2 * 64;
            float a = 0.f;
#pragma unroll 8
            for (int i = 0; i < 64; ++i)
                a += tanhf(row[i] + qv[i]) * s_svt[i];
            astore64(&spart2[scur + (long)b * 2048 + cb2 * 256 + tid], packtag(a, t));
        }

        // ---- F: per-thread poll own row; redundant argmax ----
        float v = -3.402823e38f; int vi = Sn;
        if (tid >= bd) {
            const u64t* sp = spart2 + scur + (long)b * 2048 + tid;
            u64t e0, e1, e2, e3, e4, e5, e6, e7;
            for (;;) {
                e0 = aload64(&sp[0]);    e1 = aload64(&sp[256]);
                e2 = aload64(&sp[512]);  e3 = aload64(&sp[768]);
                e4 = aload64(&sp[1024]); e5 = aload64(&sp[1280]);
                e6 = aload64(&sp[1536]); e7 = aload64(&sp[1792]);
                const unsigned tt = (unsigned)t;
                if ((unsigned)(e0 >> 32) == tt && (unsigned)(e1 >> 32) == tt &&
                    (unsigned)(e2 >> 32) == tt && (unsigned)(e3 >> 32) == tt &&
                    (unsigned)(e4 >> 32) == tt && (unsigned)(e5 >> 32) == tt &&
                    (unsigned)(e6 >> 32) == tt && (unsigned)(e7 >> 32) == tt) break;
                __builtin_amdgcn_s_sleep(1);
            }
            v = lo32(e0) + lo32(e1) + lo32(e2) + lo32(e3)
              + lo32(e4) + lo32(e5) + lo32(e6) + lo32(e7);
            vi = tid;
        }
#pragma unroll
        for (int off = 32; off; off >>= 1) {
            const float v2 = __shfl_xor(v, off, 64);
            const int   i2 = __shfl_xor(vi, off, 64);
            if (v2 > v || (v2 == v && i2 < vi)) { v = v2; vi = i2; }
        }
        if (lane == 0) { s_wv[wv] = v; s_wi[wv] = vi; }
        __syncthreads();
        {
            float bv = s_wv[0]; int bi_ = s_wi[0];
#pragma unroll
            for (int k = 1; k < 4; ++k)
                if (s_wv[k] > bv || (s_wv[k] == bv && s_wi[k] < bi_)) { bv = s_wv[k]; bi_ = s_wi[k]; }
            const int nb = (bi_ > bd) ? bi_ : bd + 1;
            if (cb2 == 0 && tid == 0 && nb < Sn) out[nb * Bn + b] = 1.0f;
            ls = bd; bd = nb;
        }
        __syncthreads();
        if (bd >= Sn) break;

        // ---- TAIL: gates for t+1 ----
        const long nxt = (long)((t + 1) & 1) * 32768;
        // issue pe row loads (x = (pe[bd]-pe[ls])*inv)
        const float2 pa  = pef2[((long)b * 257 + bd) * 256 + tid];
        const float2 pb_ = pef2[((long)b * 257 + ls) * 256 + tid];
        // E1: gph(t+1) slice (256 cols) from L2-resident WhB
        {
            float4 acc = make_float4(0.f, 0.f, 0.f, 0.f);
            const float* wb = WhB + (long)cb2 * 131072;
            const int k0 = wv * 128;
#pragma unroll 4
            for (int k = k0; k < k0 + 128; ++k) {
                const float hk = hld[k];
                const float4 w = *(const float4*)&wb[(long)k * 256 + lane * 4];
                acc.x += hk * w.x; acc.y += hk * w.y; acc.z += hk * w.z; acc.w += hk * w.w;
            }
            *(float4*)&sgp[wv][lane * 4] = acc;
        }
        // x -> LDS (pe loads have landed by now)
        {
            const float inv = 1.0f / (float)max(bd - ls, 1);
            xld[2 * tid]     = (pa.x - pb_.x) * inv;
            xld[2 * tid + 1] = (pa.y - pb_.y) * inv;
        }
        __syncthreads();
        if (tid < 128) {
            const int c0 = 2 * tid, c1 = c0 + 1;
            const float lo = sgp[0][c0] + sgp[1][c0] + sgp[2][c0] + sgp[3][c0];
            const float hi = sgp[0][c1] + sgp[1][c1] + sgp[2][c1] + sgp[3][c1];
            astore64(&gph64[nxt + (long)b * 1024 + cb2 * 128 + tid], pack2(lo, hi));
        }
        __syncthreads();
        // E2: gxw(t+1) slice from L2-resident WxB
        {
            float4 acc = make_float4(0.f, 0.f, 0.f, 0.f);
            const float* wb = WxB + (long)cb2 * 131072;
            const int k0 = wv * 128;
#pragma unroll 4
            for (int k = k0; k < k0 + 128; ++k) {
                const float xk = xld[k];
                const float4 w = *(const float4*)&wb[(long)k * 256 + lane * 4];
                acc.x += xk * w.x; acc.y += xk * w.y; acc.z += xk * w.z; acc.w += xk * w.w;
            }
            *(float4*)&sgp[wv][lane * 4] = acc;
        }
        __syncthreads();
        if (tid < 128) {
            const int c0 = 2 * tid, c1 = c0 + 1;
            const float lo = sgp[0][c0] + sgp[1][c0] + sgp[2][c0] + sgp[3][c0];
            const float hi = sgp[0][c1] + sgp[1][c1] + sgp[2][c1] + sgp[3][c1];
            astore64(&gxw64[nxt + (long)b * 1024 + cb2 * 128 + tid], pack2(lo, hi));
        }
        __syncthreads();   // drains all gate stores (vmcnt 0)
        if (tid == 0) aistore(&gflag[16 * b + cb2], t + 1);
    }
}

extern "C" void kernel_launch(void* const* d_in, const int* in_sizes, int n_in,
                              void* d_out, int out_size, void* d_ws, size_t ws_size,
                              hipStream_t stream)
{
    const int*   wid  = (const int*)d_in[0];
    const float* enc  = (const float*)d_in[1];
    const float* hn0  = (const float*)d_in[2];
    const float* emb  = (const float*)d_in[3];
    // d_in[4] chunk_emb : unused (uniform score shift, argmax-invariant)
    const float* W1   = (const float*)d_in[5];
    const float* W2   = (const float*)d_in[6];
    const float* W3   = (const float*)d_in[7];
    const float* W4   = (const float*)d_in[8];
    const float* vt1  = (const float*)d_in[9];
    // d_in[10] vt2 : unused
    const float* Wx   = (const float*)d_in[11];
    const float* Wh   = (const float*)d_in[12];
    const float* bias = (const float*)d_in[13];

    float* ws    = (float*)d_ws;
    float* bsum  = ws + OFF_BSUM;
    float* u3    = ws + OFF_U3;
    float* pe    = ws + OFF_PE;
    float* WxB   = ws + OFF_WXB;
    float* WhB   = ws + OFF_WHB;
    float* W4B   = ws + OFF_W4B;
    float* gxw   = ws + OFF_GXW;
    float* gph   = ws + OFF_GPH;
    float* sp2f  = ws + OFF_SPART;
    u64t*  sp2   = (u64t*)sp2f;
    int*   state = (int*)(ws + OFF_STATE);
    float* out   = (float*)d_out;
    float* pb    = ws + OFF_BSUM;   // pe1 partials overlay bsum (bsum_gemm runs after pe2)

    (void)hipMemsetAsync(d_out, 0, (size_t)Sn * Bn * sizeof(float), stream);
    hipLaunchKernelGGL(init_kernel, dim3(1024), dim3(256), 0, stream, gxw, gph, sp2f, state);
    hipLaunchKernelGGL(wtrans_kernel, dim3(4096), dim3(256), 0, stream, Wx, Wh, W4, WxB, WhB, W4B);
    hipLaunchKernelGGL(pe1_kernel, dim3(32, 16), dim3(256), 0, stream, wid, emb, pb);
    hipLaunchKernelGGL(pe2_kernel, dim3(32, 16), dim3(256), 0, stream, wid, emb, pb, pe);
    hipLaunchKernelGGL(u3_gemm, dim3(8, 128), dim3(256), 0, stream, wid, emb, W3, u3);
    hipLaunchKernelGGL(bsum_gemm, dim3(8, 128), dim3(256), 0, stream, enc, wid, emb, W1, W2, bsum);

    void* args[] = { (void*)&bias, (void*)&vt1, (void*)&bsum, (void*)&u3, (void*)&pe,
                     (void*)&WxB, (void*)&WhB, (void*)&W4B, (void*)&gxw, (void*)&gph,
                     (void*)&sp2, (void*)&state, (void*)&hn0, (void*)&out };
    (void)hipLaunchCooperativeKernel((void*)decode_kernel, dim3(256), dim3(256), args, 0, stream);
}